// Round 7
// baseline (173.347 us; speedup 1.0000x reference)
//
#include <hip/hip_runtime.h>
#include <hip/hip_bf16.h>
#include <cstdint>

// DoubleGRU fused kernel: 13 x (B,128)@(128,128) GEMMs + GRU gates, one pass.
// bf16 MFMA (16x16x32), fp32 accumulate/elementwise. Weights pre-packed to
// B-fragment layout in d_ws by pack_weights.
// R6: merged gate pairs, slot-XOR swizzle (133us best).
// R7: 8 thin waves (64x16 tile each, acc[4]) -> 24 waves/CU at 3 blocks/CU;
//     coalesced float4 epilogue via LDS restage (fix partial-line writes).

typedef __attribute__((ext_vector_type(8))) short bf16x8;   // 8 bf16 = 4 VGPR
typedef __attribute__((ext_vector_type(4))) float f32x4;    // acc fragment

#define S 128
#define BM 64
#define THREADS 512   // 8 waves, each: all 64 rows x its 16-col group

// LDS swizzle: byte ^= slot(row)<<4. slot = (row&7) ^ ((row>>2)&2) gives
// rows {r, r+4, r+8, r+12} 4 distinct slots (conflict-free C-scatter) while
// b128 row-octet A-reads stay 2-way (free).
#define SWZB(row) (((((row) & 7) ^ (((row) >> 2) & 2))) << 4)

__device__ __forceinline__ unsigned short f2bf(float f) {
    unsigned int u = __builtin_bit_cast(unsigned int, f);
    u += 0x7fffu + ((u >> 16) & 1u);          // round-to-nearest-even
    return (unsigned short)(u >> 16);
}
__device__ __forceinline__ float bf2f(unsigned short h) {
    unsigned int u = ((unsigned int)h) << 16;
    return __builtin_bit_cast(float, u);
}

// fast activations: v_exp_f32 + v_rcp_f32 (~1ulp each, fine vs 9.4e-2 tol)
__device__ __forceinline__ float fast_sig(float t) {
    float e = __expf(-t);
    return __builtin_amdgcn_rcpf(1.0f + e);
}
__device__ __forceinline__ float fast_tanh(float t) {
    float tc = fminf(fmaxf(t, -15.0f), 15.0f);
    float e = __expf(2.0f * tc);
    return (e - 1.0f) * __builtin_amdgcn_rcpf(e + 1.0f);
}

// ---------------- weight pre-pack: fp32 [k][n] -> bf16 B-fragments ----------
// dst layout per matrix (16384 ushort): frag = kt*8+ntg (kt:K/32, ntg:N/16),
// 512 ushort per frag; lane l holds W[kt*32+(l>>4)*8+j][ntg*16+(l&15)], j=0..7.
__global__ void pack_weights(const float* __restrict__ wx1,
                             const float* __restrict__ wx2,
                             const float* __restrict__ wh,
                             const float* __restrict__ mid,
                             unsigned short* __restrict__ dst) {
    int mat = blockIdx.x;                 // 0..12
    const float* src;
    if (mat < 3)       src = wx1 + mat * (S * S);
    else if (mat < 6)  src = wx2 + (mat - 3) * (S * S);
    else if (mat < 12) src = wh  + (mat - 6) * (S * S);
    else               src = mid;
    int t = threadIdx.x;                  // 256 threads
    for (int f8 = 0; f8 < 8; ++f8) {
        int slot = f8 * 256 + t;          // 0..2047
        int frag = slot >> 6;             // 0..31
        int lane = slot & 63;
        int kt  = frag >> 3;
        int ntg = frag & 7;
        int k0  = kt * 32 + (lane >> 4) * 8;
        int col = ntg * 16 + (lane & 15);
        unsigned int w[4];
#pragma unroll
        for (int p = 0; p < 4; ++p) {
            unsigned int lo = f2bf(src[(k0 + 2 * p) * S + col]);
            unsigned int hi = f2bf(src[(k0 + 2 * p + 1) * S + col]);
            w[p] = lo | (hi << 16);
        }
        uint4* d = (uint4*)(dst + (size_t)mat * (S * S) + frag * 512 + lane * 8);
        *d = make_uint4(w[0], w[1], w[2], w[3]);
    }
}

// ---------------- LDS helpers ------------------------------------------------
__device__ __forceinline__ bf16x8 lds_afrag(const unsigned short* s, int row, int kt, int lane) {
    int byte = row * 256 + kt * 64 + ((lane >> 4) << 4);
    byte ^= SWZB(row);
    return *(const bf16x8*)((const char*)s + byte);
}
__device__ __forceinline__ void st_bf(unsigned short* s, int row, int col, float v) {
    int byte = (row * 256 + col * 2) ^ SWZB(row);
    *(unsigned short*)((char*)s + byte) = f2bf(v);
}
__device__ __forceinline__ float ld_bf(const unsigned short* s, int row, int col) {
    int byte = (row * 256 + col * 2) ^ SWZB(row);
    return bf2f(*(const unsigned short*)((const char*)s + byte));
}

// ---------------- GEMM cores (per-wave tile: 64 rows x 16 cols) -------------
// acc += A@W, K=128. 16 MFMA, 16 ds_read_b128, 4 B-frag loads.
__device__ __forceinline__ void gemm_single(f32x4 (&acc)[4],
        const unsigned short* sA,
        const unsigned short* __restrict__ w0,
        int lane, int wc) {
    int rbase = lane & 15;
    __builtin_amdgcn_s_setprio(1);
#pragma unroll
    for (int kt = 0; kt < 4; ++kt) {
        bf16x8 a0[4];
#pragma unroll
        for (int m = 0; m < 4; ++m)
            a0[m] = lds_afrag(sA, rbase + m * 16, kt, lane);
        bf16x8 b0 = *(const bf16x8*)(w0 + (kt * 8 + wc) * 512 + lane * 8);
#pragma unroll
        for (int m = 0; m < 4; ++m)
            acc[m] = __builtin_amdgcn_mfma_f32_16x16x32_bf16(a0[m], b0, acc[m], 0, 0, 0);
    }
    __builtin_amdgcn_s_setprio(0);
}

// acc0 += A@W0, acc1 += A@W1 -- shared A-fragments, 2x independent chains.
__device__ __forceinline__ void gemm_pair2(f32x4 (&acc0)[4], f32x4 (&acc1)[4],
        const unsigned short* sA,
        const unsigned short* __restrict__ w0,
        const unsigned short* __restrict__ w1,
        int lane, int wc) {
    int rbase = lane & 15;
    __builtin_amdgcn_s_setprio(1);
#pragma unroll
    for (int kt = 0; kt < 4; ++kt) {
        bf16x8 a0[4];
#pragma unroll
        for (int m = 0; m < 4; ++m)
            a0[m] = lds_afrag(sA, rbase + m * 16, kt, lane);
        bf16x8 b0 = *(const bf16x8*)(w0 + (kt * 8 + wc) * 512 + lane * 8);
        bf16x8 b1 = *(const bf16x8*)(w1 + (kt * 8 + wc) * 512 + lane * 8);
#pragma unroll
        for (int m = 0; m < 4; ++m) {
            acc0[m] = __builtin_amdgcn_mfma_f32_16x16x32_bf16(a0[m], b0, acc0[m], 0, 0, 0);
            acc1[m] = __builtin_amdgcn_mfma_f32_16x16x32_bf16(a0[m], b1, acc1[m], 0, 0, 0);
        }
    }
    __builtin_amdgcn_s_setprio(0);
}

// bias + activation. OP: 0=sigmoid, 1=tanh. bias by value (wave col-group).
template <int OP>
__device__ __forceinline__ void finish(f32x4 (&acc)[4], float bc) {
#pragma unroll
    for (int m = 0; m < 4; ++m)
#pragma unroll
        for (int i = 0; i < 4; ++i) {
            float t = acc[m][i] + bc;
            acc[m][i] = (OP == 0) ? fast_sig(t) : fast_tanh(t);
        }
}

#define ZERO_ACC(A)                                           \
    _Pragma("unroll") for (int m = 0; m < 4; ++m)             \
        A[m] = (f32x4){0.f, 0.f, 0.f, 0.f};

// iterate this thread's 16 output coords: body(m, i, rt, col)
#define FOR_COORDS(BODY)                                      \
    _Pragma("unroll") for (int m = 0; m < 4; ++m)             \
    _Pragma("unroll") for (int i = 0; i < 4; ++i) {           \
        int rt  = m * 16 + ((lane >> 4) << 2) + i;            \
        int col = wc * 16 + (lane & 15);                      \
        BODY                                                  \
    }

// ---------------- main fused kernel ------------------------------------------
__global__ __launch_bounds__(THREADS, 6)
void dgru_main(const float* __restrict__ x, const float* __restrict__ old_h,
               const float* __restrict__ b, const unsigned short* __restrict__ wpk,
               float* __restrict__ out) {
    __shared__ __align__(16) unsigned short sx[S * BM];   // x -> mid_x     (16KB)
    __shared__ __align__(16) unsigned short sh[S * BM];   // old_h -> mid_h (16KB)
    __shared__ __align__(16) unsigned short sg[S * BM];   // rh -> rh2 -> h (16KB)

    const int tid  = threadIdx.x;
    const int lane = tid & 63;
    const int wc   = tid >> 6;          // 0..7 (16-col group)
    const long row0 = (long)blockIdx.x * BM;

    // preload the 6 bias values this thread ever needs
    float bld[6];
#pragma unroll
    for (int j = 0; j < 6; ++j)
        bld[j] = b[j * S + wc * 16 + (lane & 15)];

    // ---- stage x -> sx, old_h -> sh (fp32 -> bf16, swizzled) ----
#pragma unroll
    for (int it = 0; it < 2; ++it) {
        int slot = it * THREADS + tid;  // 0..1023 : 64 rows x 16 col-octets
        int row  = slot >> 4;
        int c8   = slot & 15;
        const float4* px = (const float4*)(x     + (row0 + row) * S + c8 * 8);
        const float4* ph = (const float4*)(old_h + (row0 + row) * S + c8 * 8);
        float4 v0 = px[0], v1 = px[1];
        float4 u0 = ph[0], u1 = ph[1];
        int byte = (row * 256 + c8 * 16) ^ SWZB(row);
        uint4 wx, wh;
        wx.x = (unsigned)f2bf(v0.x) | ((unsigned)f2bf(v0.y) << 16);
        wx.y = (unsigned)f2bf(v0.z) | ((unsigned)f2bf(v0.w) << 16);
        wx.z = (unsigned)f2bf(v1.x) | ((unsigned)f2bf(v1.y) << 16);
        wx.w = (unsigned)f2bf(v1.z) | ((unsigned)f2bf(v1.w) << 16);
        wh.x = (unsigned)f2bf(u0.x) | ((unsigned)f2bf(u0.y) << 16);
        wh.y = (unsigned)f2bf(u0.z) | ((unsigned)f2bf(u0.w) << 16);
        wh.z = (unsigned)f2bf(u1.x) | ((unsigned)f2bf(u1.y) << 16);
        wh.w = (unsigned)f2bf(u1.z) | ((unsigned)f2bf(u1.w) << 16);
        *(uint4*)((char*)sx + byte) = wx;
        *(uint4*)((char*)sh + byte) = wh;
    }
    __syncthreads();                                      // B1

#define WP(m) (wpk + (size_t)(m) * (S * S))
    // mats: 0-2 Wx1[0..2], 3-5 Wx2[0..2], 6-11 Wh[0..5], 12 mid

    // ---- stage 1: z and r together (shared A-frags) ----
    f32x4 zz[4]; ZERO_ACC(zz);
    {
        f32x4 rr[4]; ZERO_ACC(rr);
        gemm_pair2(zz, rr, sx, WP(0), WP(1), lane, wc);
        gemm_pair2(zz, rr, sh, WP(6), WP(7), lane, wc);
        finish<0>(zz, bld[0]);                            // z = sigmoid(.. + b0)
        finish<0>(rr, bld[1]);                            // r = sigmoid(.. + b1)
        FOR_COORDS({                                      // rh = r*old_h -> sg
            float oh = ld_bf(sh, rt, col);
            st_bf(sg, rt, col, rr[m][i] * oh);
        })
    }
    __syncthreads();                                      // B2 (sg complete)

    {
        f32x4 ht[4]; ZERO_ACC(ht);
        gemm_single(ht, sx, WP(2), lane, wc);
        gemm_single(ht, sg, WP(8), lane, wc);
        finish<1>(ht, bld[2]);                            // h_tilde = tanh(.. + b2)
        // mid_h = z*old_h + (1-z)*h_tilde; own coords (disjoint per wave) ->
        // read old_h then overwrite with mid_h, no barrier in between needed.
        FOR_COORDS({
            float oh = ld_bf(sh, rt, col);
            float z  = zz[m][i];
            st_bf(sh, rt, col, z * oh + (1.0f - z) * ht[m][i]);
        })
    }
    __syncthreads();                                      // B3 (mid_h complete)

    // ---- mid_x = relu(mid_h @ mid) ----
    {
        f32x4 mx[4]; ZERO_ACC(mx);
        gemm_single(mx, sh, WP(12), lane, wc);
        FOR_COORDS({
            float v = mx[m][i];
            st_bf(sx, rt, col, v > 0.0f ? v : 0.0f);      // mid_x -> sx
        })
    }
    __syncthreads();                                      // B4 (mid_x complete)

    // ---- stage 2: z2 and r2 together (faithful reuse of Wh[0], b0 for z2) ----
    f32x4 z2[4]; ZERO_ACC(z2);
    {
        f32x4 r2[4]; ZERO_ACC(r2);
        gemm_pair2(z2, r2, sx, WP(3), WP(4), lane, wc);
        gemm_pair2(z2, r2, sh, WP(6), WP(10), lane, wc);
        finish<0>(z2, bld[0]);                            // z2 = sigmoid(.. + b0)
        finish<0>(r2, bld[4]);                            // r2 = sigmoid(.. + b4)
        FOR_COORDS({                                      // rh2 = r2*mid_h -> sg
            float mhv = ld_bf(sh, rt, col);
            st_bf(sg, rt, col, r2[m][i] * mhv);
        })
    }
    __syncthreads();                                      // B5 (rh2 complete)

    {
        f32x4 h2[4]; ZERO_ACC(h2);
        gemm_single(h2, sx, WP(5), lane, wc);
        gemm_single(h2, sg, WP(11), lane, wc);
        finish<1>(h2, bld[5]);                            // h2_tilde = tanh(.. + b5)
        // h = z2*mid_h + (1-z2)*h2_tilde, blended in place into h2
        FOR_COORDS({
            float z   = z2[m][i];
            float mhv = ld_bf(sh, rt, col);
            h2[m][i] = z * mhv + (1.0f - z) * h2[m][i];
        })
        __syncthreads();                                  // B6 (sg reads done)
        FOR_COORDS({ st_bf(sg, rt, col, h2[m][i]); })     // h -> sg (bf16)
    }
    __syncthreads();                                      // B7 (h staged)

    // ---- coalesced epilogue: row-linear b128 reads -> dense float4 stores ----
#pragma unroll
    for (int it = 0; it < 2; ++it) {
        int slot = it * THREADS + tid;  // 0..1023 : 64 rows x 16 col-octets
        int row  = slot >> 4;
        int c8   = slot & 15;
        int byte = (row * 256 + c8 * 16) ^ SWZB(row);
        bf16x8 v = *(const bf16x8*)((const char*)sg + byte);
        float4 f0, f1;
        f0.x = bf2f((unsigned short)v[0]); f0.y = bf2f((unsigned short)v[1]);
        f0.z = bf2f((unsigned short)v[2]); f0.w = bf2f((unsigned short)v[3]);
        f1.x = bf2f((unsigned short)v[4]); f1.y = bf2f((unsigned short)v[5]);
        f1.z = bf2f((unsigned short)v[6]); f1.w = bf2f((unsigned short)v[7]);
        float4* po = (float4*)(out + (row0 + row) * S + c8 * 8);
        po[0] = f0;
        po[1] = f1;
    }
}

extern "C" void kernel_launch(void* const* d_in, const int* in_sizes, int n_in,
                              void* d_out, int out_size, void* d_ws, size_t ws_size,
                              hipStream_t stream) {
    const float* x     = (const float*)d_in[0];
    const float* old_h = (const float*)d_in[1];
    const float* W_x1  = (const float*)d_in[2];
    const float* W_x2  = (const float*)d_in[3];
    const float* W_h   = (const float*)d_in[4];
    const float* b     = (const float*)d_in[5];
    const float* mid   = (const float*)d_in[6];
    float* out = (float*)d_out;
    unsigned short* wpk = (unsigned short*)d_ws;   // 13 * 32KB packed bf16 weights

    int batch = in_sizes[0] / S;                   // 131072

    pack_weights<<<13, 256, 0, stream>>>(W_x1, W_x2, W_h, mid, wpk);
    dgru_main<<<batch / BM, THREADS, 0, stream>>>(x, old_h, b, wpk, out);
}

// Round 8
// 98.524 us; speedup vs baseline: 1.7594x; 1.7594x over previous
//
#include <hip/hip_runtime.h>
#include <hip/hip_bf16.h>
#include <cstdint>

// DoubleGRU fused kernel: 13 x (B,128)@(128,128) GEMMs + GRU gates, one pass.
// bf16 MFMA (16x16x32), fp32 accumulate/elementwise. Weights pre-packed to
// B-fragment layout in d_ws by pack_weights.
// R6: merged gate pairs, slot-XOR swizzle (133us best).
// R7: 8 thin waves + coalesced epilogue, but (512,6) -> 85-reg budget -> SPILLS.
// R8: identical to R7 except __launch_bounds__(512,4): 16 waves/CU, 128-reg
//     budget -> no spills. Calibration: 24 w/CU=85 regs spills (R4,R7);
//     12 w/CU=170 regs fine (R3,R6). 16 w/CU is the sweet spot to test.

typedef __attribute__((ext_vector_type(8))) short bf16x8;   // 8 bf16 = 4 VGPR
typedef __attribute__((ext_vector_type(4))) float f32x4;    // acc fragment

#define S 128
#define BM 64
#define THREADS 512   // 8 waves, each: all 64 rows x its 16-col group

// LDS swizzle: byte ^= slot(row)<<4. slot = (row&7) ^ ((row>>2)&2) gives
// rows {r, r+4, r+8, r+12} 4 distinct slots (conflict-free C-scatter) while
// b128 row-octet A-reads stay 2-way (free).
#define SWZB(row) (((((row) & 7) ^ (((row) >> 2) & 2))) << 4)

__device__ __forceinline__ unsigned short f2bf(float f) {
    unsigned int u = __builtin_bit_cast(unsigned int, f);
    u += 0x7fffu + ((u >> 16) & 1u);          // round-to-nearest-even
    return (unsigned short)(u >> 16);
}
__device__ __forceinline__ float bf2f(unsigned short h) {
    unsigned int u = ((unsigned int)h) << 16;
    return __builtin_bit_cast(float, u);
}

// fast activations: v_exp_f32 + v_rcp_f32 (~1ulp each, fine vs 9.4e-2 tol)
__device__ __forceinline__ float fast_sig(float t) {
    float e = __expf(-t);
    return __builtin_amdgcn_rcpf(1.0f + e);
}
__device__ __forceinline__ float fast_tanh(float t) {
    float tc = fminf(fmaxf(t, -15.0f), 15.0f);
    float e = __expf(2.0f * tc);
    return (e - 1.0f) * __builtin_amdgcn_rcpf(e + 1.0f);
}

// ---------------- weight pre-pack: fp32 [k][n] -> bf16 B-fragments ----------
// dst layout per matrix (16384 ushort): frag = kt*8+ntg (kt:K/32, ntg:N/16),
// 512 ushort per frag; lane l holds W[kt*32+(l>>4)*8+j][ntg*16+(l&15)], j=0..7.
__global__ void pack_weights(const float* __restrict__ wx1,
                             const float* __restrict__ wx2,
                             const float* __restrict__ wh,
                             const float* __restrict__ mid,
                             unsigned short* __restrict__ dst) {
    int mat = blockIdx.x;                 // 0..12
    const float* src;
    if (mat < 3)       src = wx1 + mat * (S * S);
    else if (mat < 6)  src = wx2 + (mat - 3) * (S * S);
    else if (mat < 12) src = wh  + (mat - 6) * (S * S);
    else               src = mid;
    int t = threadIdx.x;                  // 256 threads
    for (int f8 = 0; f8 < 8; ++f8) {
        int slot = f8 * 256 + t;          // 0..2047
        int frag = slot >> 6;             // 0..31
        int lane = slot & 63;
        int kt  = frag >> 3;
        int ntg = frag & 7;
        int k0  = kt * 32 + (lane >> 4) * 8;
        int col = ntg * 16 + (lane & 15);
        unsigned int w[4];
#pragma unroll
        for (int p = 0; p < 4; ++p) {
            unsigned int lo = f2bf(src[(k0 + 2 * p) * S + col]);
            unsigned int hi = f2bf(src[(k0 + 2 * p + 1) * S + col]);
            w[p] = lo | (hi << 16);
        }
        uint4* d = (uint4*)(dst + (size_t)mat * (S * S) + frag * 512 + lane * 8);
        *d = make_uint4(w[0], w[1], w[2], w[3]);
    }
}

// ---------------- LDS helpers ------------------------------------------------
__device__ __forceinline__ bf16x8 lds_afrag(const unsigned short* s, int row, int kt, int lane) {
    int byte = row * 256 + kt * 64 + ((lane >> 4) << 4);
    byte ^= SWZB(row);
    return *(const bf16x8*)((const char*)s + byte);
}
__device__ __forceinline__ void st_bf(unsigned short* s, int row, int col, float v) {
    int byte = (row * 256 + col * 2) ^ SWZB(row);
    *(unsigned short*)((char*)s + byte) = f2bf(v);
}
__device__ __forceinline__ float ld_bf(const unsigned short* s, int row, int col) {
    int byte = (row * 256 + col * 2) ^ SWZB(row);
    return bf2f(*(const unsigned short*)((const char*)s + byte));
}

// ---------------- GEMM cores (per-wave tile: 64 rows x 16 cols) -------------
// acc += A@W, K=128. 16 MFMA, 16 ds_read_b128, 4 B-frag loads.
__device__ __forceinline__ void gemm_single(f32x4 (&acc)[4],
        const unsigned short* sA,
        const unsigned short* __restrict__ w0,
        int lane, int wc) {
    int rbase = lane & 15;
    __builtin_amdgcn_s_setprio(1);
#pragma unroll
    for (int kt = 0; kt < 4; ++kt) {
        bf16x8 a0[4];
#pragma unroll
        for (int m = 0; m < 4; ++m)
            a0[m] = lds_afrag(sA, rbase + m * 16, kt, lane);
        bf16x8 b0 = *(const bf16x8*)(w0 + (kt * 8 + wc) * 512 + lane * 8);
#pragma unroll
        for (int m = 0; m < 4; ++m)
            acc[m] = __builtin_amdgcn_mfma_f32_16x16x32_bf16(a0[m], b0, acc[m], 0, 0, 0);
    }
    __builtin_amdgcn_s_setprio(0);
}

// acc0 += A@W0, acc1 += A@W1 -- shared A-fragments, 2x independent chains.
__device__ __forceinline__ void gemm_pair2(f32x4 (&acc0)[4], f32x4 (&acc1)[4],
        const unsigned short* sA,
        const unsigned short* __restrict__ w0,
        const unsigned short* __restrict__ w1,
        int lane, int wc) {
    int rbase = lane & 15;
    __builtin_amdgcn_s_setprio(1);
#pragma unroll
    for (int kt = 0; kt < 4; ++kt) {
        bf16x8 a0[4];
#pragma unroll
        for (int m = 0; m < 4; ++m)
            a0[m] = lds_afrag(sA, rbase + m * 16, kt, lane);
        bf16x8 b0 = *(const bf16x8*)(w0 + (kt * 8 + wc) * 512 + lane * 8);
        bf16x8 b1 = *(const bf16x8*)(w1 + (kt * 8 + wc) * 512 + lane * 8);
#pragma unroll
        for (int m = 0; m < 4; ++m) {
            acc0[m] = __builtin_amdgcn_mfma_f32_16x16x32_bf16(a0[m], b0, acc0[m], 0, 0, 0);
            acc1[m] = __builtin_amdgcn_mfma_f32_16x16x32_bf16(a0[m], b1, acc1[m], 0, 0, 0);
        }
    }
    __builtin_amdgcn_s_setprio(0);
}

// bias + activation. OP: 0=sigmoid, 1=tanh. bias by value (wave col-group).
template <int OP>
__device__ __forceinline__ void finish(f32x4 (&acc)[4], float bc) {
#pragma unroll
    for (int m = 0; m < 4; ++m)
#pragma unroll
        for (int i = 0; i < 4; ++i) {
            float t = acc[m][i] + bc;
            acc[m][i] = (OP == 0) ? fast_sig(t) : fast_tanh(t);
        }
}

#define ZERO_ACC(A)                                           \
    _Pragma("unroll") for (int m = 0; m < 4; ++m)             \
        A[m] = (f32x4){0.f, 0.f, 0.f, 0.f};

// iterate this thread's 16 output coords: body(m, i, rt, col)
#define FOR_COORDS(BODY)                                      \
    _Pragma("unroll") for (int m = 0; m < 4; ++m)             \
    _Pragma("unroll") for (int i = 0; i < 4; ++i) {           \
        int rt  = m * 16 + ((lane >> 4) << 2) + i;            \
        int col = wc * 16 + (lane & 15);                      \
        BODY                                                  \
    }

// ---------------- main fused kernel ------------------------------------------
__global__ __launch_bounds__(THREADS, 4)
void dgru_main(const float* __restrict__ x, const float* __restrict__ old_h,
               const float* __restrict__ b, const unsigned short* __restrict__ wpk,
               float* __restrict__ out) {
    __shared__ __align__(16) unsigned short sx[S * BM];   // x -> mid_x     (16KB)
    __shared__ __align__(16) unsigned short sh[S * BM];   // old_h -> mid_h (16KB)
    __shared__ __align__(16) unsigned short sg[S * BM];   // rh -> rh2 -> h (16KB)

    const int tid  = threadIdx.x;
    const int lane = tid & 63;
    const int wc   = tid >> 6;          // 0..7 (16-col group)
    const long row0 = (long)blockIdx.x * BM;

    // preload the 6 bias values this thread ever needs
    float bld[6];
#pragma unroll
    for (int j = 0; j < 6; ++j)
        bld[j] = b[j * S + wc * 16 + (lane & 15)];

    // ---- stage x -> sx, old_h -> sh (fp32 -> bf16, swizzled) ----
#pragma unroll
    for (int it = 0; it < 2; ++it) {
        int slot = it * THREADS + tid;  // 0..1023 : 64 rows x 16 col-octets
        int row  = slot >> 4;
        int c8   = slot & 15;
        const float4* px = (const float4*)(x     + (row0 + row) * S + c8 * 8);
        const float4* ph = (const float4*)(old_h + (row0 + row) * S + c8 * 8);
        float4 v0 = px[0], v1 = px[1];
        float4 u0 = ph[0], u1 = ph[1];
        int byte = (row * 256 + c8 * 16) ^ SWZB(row);
        uint4 wx, wh;
        wx.x = (unsigned)f2bf(v0.x) | ((unsigned)f2bf(v0.y) << 16);
        wx.y = (unsigned)f2bf(v0.z) | ((unsigned)f2bf(v0.w) << 16);
        wx.z = (unsigned)f2bf(v1.x) | ((unsigned)f2bf(v1.y) << 16);
        wx.w = (unsigned)f2bf(v1.z) | ((unsigned)f2bf(v1.w) << 16);
        wh.x = (unsigned)f2bf(u0.x) | ((unsigned)f2bf(u0.y) << 16);
        wh.y = (unsigned)f2bf(u0.z) | ((unsigned)f2bf(u0.w) << 16);
        wh.z = (unsigned)f2bf(u1.x) | ((unsigned)f2bf(u1.y) << 16);
        wh.w = (unsigned)f2bf(u1.z) | ((unsigned)f2bf(u1.w) << 16);
        *(uint4*)((char*)sx + byte) = wx;
        *(uint4*)((char*)sh + byte) = wh;
    }
    __syncthreads();                                      // B1

#define WP(m) (wpk + (size_t)(m) * (S * S))
    // mats: 0-2 Wx1[0..2], 3-5 Wx2[0..2], 6-11 Wh[0..5], 12 mid

    // ---- stage 1: z and r together (shared A-frags) ----
    f32x4 zz[4]; ZERO_ACC(zz);
    {
        f32x4 rr[4]; ZERO_ACC(rr);
        gemm_pair2(zz, rr, sx, WP(0), WP(1), lane, wc);
        gemm_pair2(zz, rr, sh, WP(6), WP(7), lane, wc);
        finish<0>(zz, bld[0]);                            // z = sigmoid(.. + b0)
        finish<0>(rr, bld[1]);                            // r = sigmoid(.. + b1)
        FOR_COORDS({                                      // rh = r*old_h -> sg
            float oh = ld_bf(sh, rt, col);
            st_bf(sg, rt, col, rr[m][i] * oh);
        })
    }
    __syncthreads();                                      // B2 (sg complete)

    {
        f32x4 ht[4]; ZERO_ACC(ht);
        gemm_single(ht, sx, WP(2), lane, wc);
        gemm_single(ht, sg, WP(8), lane, wc);
        finish<1>(ht, bld[2]);                            // h_tilde = tanh(.. + b2)
        // mid_h = z*old_h + (1-z)*h_tilde; own coords (disjoint per wave) ->
        // read old_h then overwrite with mid_h, no barrier in between needed.
        FOR_COORDS({
            float oh = ld_bf(sh, rt, col);
            float z  = zz[m][i];
            st_bf(sh, rt, col, z * oh + (1.0f - z) * ht[m][i]);
        })
    }
    __syncthreads();                                      // B3 (mid_h complete)

    // ---- mid_x = relu(mid_h @ mid) ----
    {
        f32x4 mx[4]; ZERO_ACC(mx);
        gemm_single(mx, sh, WP(12), lane, wc);
        FOR_COORDS({
            float v = mx[m][i];
            st_bf(sx, rt, col, v > 0.0f ? v : 0.0f);      // mid_x -> sx
        })
    }
    __syncthreads();                                      // B4 (mid_x complete)

    // ---- stage 2: z2 and r2 together (faithful reuse of Wh[0], b0 for z2) ----
    f32x4 z2[4]; ZERO_ACC(z2);
    {
        f32x4 r2[4]; ZERO_ACC(r2);
        gemm_pair2(z2, r2, sx, WP(3), WP(4), lane, wc);
        gemm_pair2(z2, r2, sh, WP(6), WP(10), lane, wc);
        finish<0>(z2, bld[0]);                            // z2 = sigmoid(.. + b0)
        finish<0>(r2, bld[4]);                            // r2 = sigmoid(.. + b4)
        FOR_COORDS({                                      // rh2 = r2*mid_h -> sg
            float mhv = ld_bf(sh, rt, col);
            st_bf(sg, rt, col, r2[m][i] * mhv);
        })
    }
    __syncthreads();                                      // B5 (rh2 complete)

    {
        f32x4 h2[4]; ZERO_ACC(h2);
        gemm_single(h2, sx, WP(5), lane, wc);
        gemm_single(h2, sg, WP(11), lane, wc);
        finish<1>(h2, bld[5]);                            // h2_tilde = tanh(.. + b5)
        // h = z2*mid_h + (1-z2)*h2_tilde, blended in place into h2
        FOR_COORDS({
            float z   = z2[m][i];
            float mhv = ld_bf(sh, rt, col);
            h2[m][i] = z * mhv + (1.0f - z) * h2[m][i];
        })
        __syncthreads();                                  // B6 (sg reads done)
        FOR_COORDS({ st_bf(sg, rt, col, h2[m][i]); })     // h -> sg (bf16)
    }
    __syncthreads();                                      // B7 (h staged)

    // ---- coalesced epilogue: row-linear b128 reads -> dense float4 stores ----
#pragma unroll
    for (int it = 0; it < 2; ++it) {
        int slot = it * THREADS + tid;  // 0..1023 : 64 rows x 16 col-octets
        int row  = slot >> 4;
        int c8   = slot & 15;
        int byte = (row * 256 + c8 * 16) ^ SWZB(row);
        bf16x8 v = *(const bf16x8*)((const char*)sg + byte);
        float4 f0, f1;
        f0.x = bf2f((unsigned short)v[0]); f0.y = bf2f((unsigned short)v[1]);
        f0.z = bf2f((unsigned short)v[2]); f0.w = bf2f((unsigned short)v[3]);
        f1.x = bf2f((unsigned short)v[4]); f1.y = bf2f((unsigned short)v[5]);
        f1.z = bf2f((unsigned short)v[6]); f1.w = bf2f((unsigned short)v[7]);
        float4* po = (float4*)(out + (row0 + row) * S + c8 * 8);
        po[0] = f0;
        po[1] = f1;
    }
}

extern "C" void kernel_launch(void* const* d_in, const int* in_sizes, int n_in,
                              void* d_out, int out_size, void* d_ws, size_t ws_size,
                              hipStream_t stream) {
    const float* x     = (const float*)d_in[0];
    const float* old_h = (const float*)d_in[1];
    const float* W_x1  = (const float*)d_in[2];
    const float* W_x2  = (const float*)d_in[3];
    const float* W_h   = (const float*)d_in[4];
    const float* b     = (const float*)d_in[5];
    const float* mid   = (const float*)d_in[6];
    float* out = (float*)d_out;
    unsigned short* wpk = (unsigned short*)d_ws;   // 13 * 32KB packed bf16 weights

    int batch = in_sizes[0] / S;                   // 131072

    pack_weights<<<13, 256, 0, stream>>>(W_x1, W_x2, W_h, mid, wpk);
    dgru_main<<<batch / BM, THREADS, 0, stream>>>(x, old_h, b, wpk, out);
}